// Round 7
// baseline (666.175 us; speedup 1.0000x reference)
//
#include <hip/hip_runtime.h>

// RevRNN forward on MI355X — round 7:
//  * cells: r6 gemm8p unchanged (256x256 BK=64, 8-phase, verified ledger)
//  * decoder: NEW gemm2b — BM=256,BN=128,BK=32, ring-3 LDS (72KB) -> 2 blocks/CU
//    so the fp32 C-store epilogue overlaps the other block's K-loop.
//  * aux fusion: {convW1+convW2+gather} one kernel; {act4+convDec} one kernel.
//
// ws layout (bytes):
//   A    @ 0         [4096][2048] bf16  16.8 MB
//   z    @ 16777216  [4096][3072] bf16  25.2 MB (live until act4)
//   cWb1 @ 44040192  [6144][2048] bf16  25.2 MB (dead after cell1 gemm2)
//   cWb2 @ 69206016  [6144][2048] bf16  25.2 MB (dead after cell2 gemm2)
//   dWb  @ 44040192  [32000][1024] bf16 65.5 MB (written at act4; overlaps dead cWb*)

typedef __attribute__((ext_vector_type(4))) float f32x4;
typedef __attribute__((ext_vector_type(8))) short bf16x8;
typedef __attribute__((ext_vector_type(4))) unsigned short u16x4;

__device__ __forceinline__ unsigned short f2bf(float x) {
  unsigned u = __float_as_uint(x);
  return (unsigned short)((u + 0x7fffu + ((u >> 16) & 1u)) >> 16);  // RNE
}
__device__ __forceinline__ float bf2f(unsigned short h) {
  return __uint_as_float(((unsigned)h) << 16);
}
__device__ __forceinline__ u16x4 cvt4v(f32x4 v) {
  u16x4 h;
  h[0] = f2bf(v[0]); h[1] = f2bf(v[1]); h[2] = f2bf(v[2]); h[3] = f2bf(v[3]);
  return h;
}
__device__ __forceinline__ float sigf(float x) { return 1.0f / (1.0f + expf(-x)); }

__device__ __forceinline__ void conv_chunk(const float* __restrict__ src,
                                           unsigned short* __restrict__ dst,
                                           long i, long n4) {
  if (i >= n4) return;
  f32x4 v = __builtin_nontemporal_load(reinterpret_cast<const f32x4*>(src) + i);
  reinterpret_cast<u16x4*>(dst)[i] = cvt4v(v);
}

// ---- fused: convW1 + convW2 + gather_cat ----
__global__ void fused_pre(const float* __restrict__ W1, unsigned short* __restrict__ cWb1,
                          const float* __restrict__ W2, unsigned short* __restrict__ cWb2,
                          const int* __restrict__ ids, const float* __restrict__ embW,
                          const float* __restrict__ h1, unsigned short* __restrict__ A) {
  const long n4 = 6L * 1024 * 2048 / 4;           // 3,145,728 -> 12288 blocks each
  int b = blockIdx.x;
  int t = threadIdx.x;
  if (b < 12288) {
    conv_chunk(W1, cWb1, (long)b * 256 + t, n4);
  } else if (b < 24576) {
    conv_chunk(W2, cWb2, (long)(b - 12288) * 256 + t, n4);
  } else {
    int r = b - 24576;                            // 4096 gather rows
    long erow = (long)ids[r] * 1024;
    f32x4 e = reinterpret_cast<const f32x4*>(embW + erow)[t];
    f32x4 h = reinterpret_cast<const f32x4*>(h1 + (long)r * 1024)[t];
    reinterpret_cast<u16x4*>(A + (long)r * 2048)[t] = cvt4v(e);
    reinterpret_cast<u16x4*>(A + (long)r * 2048 + 1024)[t] = cvt4v(h);
  }
}

// ---- gate activation (z bf16); optional fused decoder-weight conversion ----
// swap01=0: out=(sig(z0)*prev+sig(z1)*tanh(z2))*0.5 ; swap01=1: z0<->z1 roles
__global__ void act_gate(const unsigned short* __restrict__ z, const float* __restrict__ prev,
                         float* __restrict__ outf, unsigned short* __restrict__ obf,
                         int swap01,
                         const float* __restrict__ xsrc, unsigned short* __restrict__ xbf,
                         const float* __restrict__ cvsrc, unsigned short* __restrict__ cvdst,
                         long cvblocks, long cvn4) {
  long b = blockIdx.x;
  int t = threadIdx.x;
  if (b < cvblocks) {                             // fused conv part (decoder weights)
    conv_chunk(cvsrc, cvdst, b * 256 + t, cvn4);
    return;
  }
  b -= cvblocks;
  long zb = b * 3072;
  u16x4 u0 = reinterpret_cast<const u16x4*>(z + zb)[t];
  u16x4 u1 = reinterpret_cast<const u16x4*>(z + zb + 1024)[t];
  u16x4 u2 = reinterpret_cast<const u16x4*>(z + zb + 2048)[t];
  if (swap01) { u16x4 tmp = u0; u0 = u1; u1 = tmp; }
  f32x4 p = reinterpret_cast<const f32x4*>(prev + b * 1024)[t];
  f32x4 o;
#pragma unroll
  for (int k = 0; k < 4; ++k)
    o[k] = (sigf(bf2f(u0[k])) * p[k] + sigf(bf2f(u1[k])) * tanhf(bf2f(u2[k]))) * 0.5f;
  __builtin_nontemporal_store(o, reinterpret_cast<f32x4*>(outf + b * 1024) + t);
  reinterpret_cast<u16x4*>(obf + b * 2048)[t] = cvt4v(o);
  if (xsrc) {
    f32x4 x = reinterpret_cast<const f32x4*>(xsrc + b * 1024)[t];
    reinterpret_cast<u16x4*>(xbf + b * 2048)[t] = cvt4v(x);
  }
}

// ---- async global->LDS 16B ----
__device__ __forceinline__ void load16(const void* g, void* l) {
  __builtin_amdgcn_global_load_lds((const __attribute__((address_space(1))) unsigned int*)g,
                                   (__attribute__((address_space(3))) unsigned int*)l,
                                   16, 0, 0);
}

#define WAITV(n) do { asm volatile("s_waitcnt vmcnt(" #n ")" ::: "memory");      \
    __builtin_amdgcn_sched_barrier(0); } while (0)
#define WAITL() do { asm volatile("s_waitcnt lgkmcnt(0)" ::: "memory");          \
    __builtin_amdgcn_sched_barrier(0); } while (0)
#define BAR() __builtin_amdgcn_s_barrier()

// ================= 8-phase 256x256 bf16 GEMM (cells; r6-verified) =================
template <bool BF16OUT>
__global__ __launch_bounds__(512, 2) void gemm8p(
    const unsigned short* __restrict__ A, int lda,
    const unsigned short* __restrict__ B, int ldb,
    const float* __restrict__ bias, void* __restrict__ Cv, long ldc, int K) {
  __shared__ unsigned short lds[2][4][8192];  // 128 KiB

  const int gx = gridDim.x;
  const int nwg = gx * gridDim.y;
  int bid = blockIdx.y * gx + blockIdx.x;
  const int q = nwg >> 3;
  const int x = bid & 7, j = bid >> 3;
  const int p = x >> 1, half = x & 1;
  const int w0 = (gx + 1) >> 1;
  int bx, byl;
  if ((w0 << 2) == q) {
    bx = half * w0 + (j >> 2);
    byl = j & 3;
  } else {
    if (j < q - 2) {
      bx = (half ? w0 : 0) + (j >> 2);
      byl = j & 3;
    } else {
      bx = w0 - 1;
      byl = (half ? 2 : 0) + (j - (q - 2));
    }
  }
  const int by = p * 4 + byl;
  const long m0 = (long)by * 256;
  const long n0 = (long)bx * 256;

  const int tid = threadIdx.x;
  const int lane = tid & 63;
  const int wave = tid >> 6;
  const int wr = wave >> 2;
  const int wc = wave & 3;
  const int lr = lane & 15;
  const int lq = lane >> 4;
  const int kb = lq * 16;

  const int o0 = tid * 16, o1 = tid * 16 + 8192;
  const int q0 = o0 ^ (((o0 >> 7) & 3) << 4);
  const int q1 = o1 ^ (((o1 >> 7) & 3) << 4);
  const char* pa0 = (const char*)(A + (m0 + (q0 >> 6)) * lda) + (q0 & 63);
  const char* pa1 = (const char*)(A + (m0 + (q1 >> 6)) * lda) + (q1 & 63);
  const char* pb0 = (const char*)(B + (n0 + (q0 >> 6)) * ldb) + (q0 & 63);
  const char* pb1 = (const char*)(B + (n0 + (q1 >> 6)) * ldb) + (q1 & 63);

  const int NT = K >> 6;

#define STG_A(t_, kh_) do { int ko = ((t_) << 7) + ((kh_) << 6);                 \
    char* d = (char*)&lds[(t_) & 1][(kh_) ? 2 : 0][0];                           \
    load16(pa0 + ko, d + o0); load16(pa1 + ko, d + o1); } while (0)
#define STG_B(t_, kh_) do { int ko = ((t_) << 7) + ((kh_) << 6);                 \
    char* d = (char*)&lds[(t_) & 1][(kh_) ? 3 : 1][0];                           \
    load16(pb0 + ko, d + o0); load16(pb1 + ko, d + o1); } while (0)

  f32x4 acc[8][4] = {};
  bf16x8 af[4], bf[4];

  STG_B(0, 0); STG_A(0, 0); STG_B(0, 1); STG_A(0, 1);
  STG_B(1, 0); STG_A(1, 0); STG_B(1, 1);
  WAITV(6);
  BAR();

  for (int t = 0; t < NT; ++t) {
    const int cur = t & 1;
    // phase 0
#pragma unroll
    for (int i = 0; i < 4; ++i) {
      int o = (wr * 128 + i * 16 + lr) * 64 + kb;
      o ^= ((o >> 7) & 3) << 4;
      af[i] = *(const bf16x8*)((const char*)&lds[cur][0][0] + o);
    }
#pragma unroll
    for (int jj = 0; jj < 4; ++jj) {
      int o = (wc * 64 + jj * 16 + lr) * 64 + kb;
      o ^= ((o >> 7) & 3) << 4;
      bf[jj] = *(const bf16x8*)((const char*)&lds[cur][1][0] + o);
    }
    if (t + 1 < NT) STG_A(t + 1, 1);
    BAR();
    WAITL();
    __builtin_amdgcn_s_setprio(1);
#pragma unroll
    for (int i = 0; i < 4; ++i)
#pragma unroll
      for (int jj = 0; jj < 4; ++jj)
        acc[i][jj] = __builtin_amdgcn_mfma_f32_16x16x32_bf16(af[i], bf[jj], acc[i][jj], 0, 0, 0);
    __builtin_amdgcn_s_setprio(0);
    BAR();
    // phase 1
#pragma unroll
    for (int i = 0; i < 4; ++i) {
      int o = (wr * 128 + (i + 4) * 16 + lr) * 64 + kb;
      o ^= ((o >> 7) & 3) << 4;
      af[i] = *(const bf16x8*)((const char*)&lds[cur][0][0] + o);
    }
    if (t + 2 < NT) STG_B(t + 2, 0);
    BAR();
    WAITL();
    __builtin_amdgcn_s_setprio(1);
#pragma unroll
    for (int i = 0; i < 4; ++i)
#pragma unroll
      for (int jj = 0; jj < 4; ++jj)
        acc[i + 4][jj] = __builtin_amdgcn_mfma_f32_16x16x32_bf16(af[i], bf[jj], acc[i + 4][jj], 0, 0, 0);
    __builtin_amdgcn_s_setprio(0);
    BAR();
    // phase 2
#pragma unroll
    for (int i = 0; i < 4; ++i) {
      int o = (wr * 128 + i * 16 + lr) * 64 + kb;
      o ^= ((o >> 7) & 3) << 4;
      af[i] = *(const bf16x8*)((const char*)&lds[cur][2][0] + o);
    }
#pragma unroll
    for (int jj = 0; jj < 4; ++jj) {
      int o = (wc * 64 + jj * 16 + lr) * 64 + kb;
      o ^= ((o >> 7) & 3) << 4;
      bf[jj] = *(const bf16x8*)((const char*)&lds[cur][3][0] + o);
    }
    if (t + 2 < NT) STG_A(t + 2, 0);
    BAR();
    WAITL();
    __builtin_amdgcn_s_setprio(1);
#pragma unroll
    for (int i = 0; i < 4; ++i)
#pragma unroll
      for (int jj = 0; jj < 4; ++jj)
        acc[i][jj] = __builtin_amdgcn_mfma_f32_16x16x32_bf16(af[i], bf[jj], acc[i][jj], 0, 0, 0);
    __builtin_amdgcn_s_setprio(0);
    BAR();
    // phase 3
#pragma unroll
    for (int i = 0; i < 4; ++i) {
      int o = (wr * 128 + (i + 4) * 16 + lr) * 64 + kb;
      o ^= ((o >> 7) & 3) << 4;
      af[i] = *(const bf16x8*)((const char*)&lds[cur][2][0] + o);
    }
    if (t + 2 < NT) STG_B(t + 2, 1);
    BAR();
    WAITL();
    __builtin_amdgcn_s_setprio(1);
#pragma unroll
    for (int i = 0; i < 4; ++i)
#pragma unroll
      for (int jj = 0; jj < 4; ++jj)
        acc[i + 4][jj] = __builtin_amdgcn_mfma_f32_16x16x32_bf16(af[i], bf[jj], acc[i + 4][jj], 0, 0, 0);
    __builtin_amdgcn_s_setprio(0);
    if (t <= NT - 3) { WAITV(6); }
    else if (t == NT - 2) { WAITV(0); }
    BAR();
  }

  float* Tw = (float*)&lds[0][0][0] + wave * 2176;
  f32x4 bv4 = *(const f32x4*)&bias[n0 + wc * 64 + lr * 4];
#pragma unroll
  for (int i = 0; i < 8; ++i) {
    float* T = Tw + (i & 1) * 1088;
#pragma unroll
    for (int jj = 0; jj < 4; ++jj)
#pragma unroll
      for (int qq = 0; qq < 4; ++qq)
        T[(lq * 4 + qq) * 68 + jj * 16 + lr] = acc[i][jj][qq];
#pragma unroll
    for (int s = 0; s < 4; ++s) {
      f32x4 v = *(const f32x4*)&T[(s * 4 + lq) * 68 + lr * 4];
      v += bv4;
      long row = m0 + wr * 128 + i * 16 + s * 4 + lq;
      long cix = row * ldc + n0 + wc * 64 + lr * 4;
      if (BF16OUT) {
        *(u16x4*)((unsigned short*)Cv + cix) = cvt4v(v);
      } else {
        __builtin_nontemporal_store(v, (f32x4*)((float*)Cv + cix));
      }
    }
  }
#undef STG_A
#undef STG_B
}

// ======== decoder GEMM: BM=256, BN=128, BK=32, ring-3 LDS, 2 blocks/CU ========
// Ledger: tile t reads buf[t%3]; stages go to buf[(t+2)%3] whose last reader
// was tile t-1 (barrier-separated -> safe). Per tile 3 loads in flight ->
// vmcnt(3) steady, vmcnt(0) at t==NT-2. 2 phases/tile, 8 MFMA each.
__global__ __launch_bounds__(512, 4) void gemm2b(
    const unsigned short* __restrict__ A, int lda,
    const unsigned short* __restrict__ B, int ldb,
    const float* __restrict__ bias, float* __restrict__ C, long ldc, int K) {
  __shared__ unsigned short lds[3][12288];  // 3 x (A 16KB + B 8KB) = 72 KiB

  const int gx = gridDim.x;                    // 250
  const int nwg = gx * gridDim.y;              // gy=16
  int bid = blockIdx.y * gx + blockIdx.x;
  const int q = nwg >> 3;                      // 500
  const int x = bid & 7, j = bid >> 3;
  const int p = x >> 1, half = x & 1;
  const int w0 = (gx + 1) >> 1;                // 125; 4*125==500 -> even path
  int bx, byl;
  if ((w0 << 2) == q) {
    bx = half * w0 + (j >> 2);
    byl = j & 3;
  } else {
    if (j < q - 2) { bx = (half ? w0 : 0) + (j >> 2); byl = j & 3; }
    else { bx = w0 - 1; byl = (half ? 2 : 0) + (j - (q - 2)); }
  }
  const int by = p * 4 + byl;
  const long m0 = (long)by * 256;
  const long n0 = (long)bx * 128;

  const int tid = threadIdx.x;
  const int lane = tid & 63;
  const int wave = tid >> 6;
  const int wr = wave >> 2;                    // 0..1 (128 rows)
  const int wc = wave & 3;                     // 0..3 (32 cols)
  const int lr = lane & 15;
  const int lq = lane >> 4;
  const int kb = lq * 16;

  const int o0 = tid * 16, o1 = tid * 16 + 8192;
  const int q0 = o0 ^ (((o0 >> 7) & 3) << 4);
  const int q1 = o1 ^ (((o1 >> 7) & 3) << 4);
  const char* pa0 = (const char*)(A + (m0 + (q0 >> 6)) * lda) + (q0 & 63);
  const char* pa1 = (const char*)(A + (m0 + (q1 >> 6)) * lda) + (q1 & 63);
  const char* pb0 = (const char*)(B + (n0 + (q0 >> 6)) * ldb) + (q0 & 63);

  const int NT = K >> 5;                       // BK=32 -> 64B per tile row-chunk

#define STG2_A(t_) do { int ko = (t_) << 6;                                      \
    char* d = (char*)&lds[(t_) % 3][0];                                          \
    load16(pa0 + ko, d + o0); load16(pa1 + ko, d + o1); } while (0)
#define STG2_B(t_) do { int ko = (t_) << 6;                                      \
    char* d = (char*)&lds[(t_) % 3][8192];                                       \
    load16(pb0 + ko, d + o0); } while (0)

  f32x4 acc[8][2] = {};
  bf16x8 af[4], bf[2];

  // prologue: tiles 0,1 (3 loads each); wait tile 0 complete
  STG2_A(0); STG2_B(0); STG2_A(1); STG2_B(1);
  WAITV(3);
  BAR();

  for (int t = 0; t < NT; ++t) {
    const unsigned short* buf = &lds[t % 3][0];
    // -------- phase 0: i0-3 x j0-1 --------
#pragma unroll
    for (int i = 0; i < 4; ++i) {
      int o = (wr * 128 + i * 16 + lr) * 64 + kb;
      o ^= ((o >> 7) & 3) << 4;
      af[i] = *(const bf16x8*)((const char*)buf + o);
    }
#pragma unroll
    for (int jj = 0; jj < 2; ++jj) {
      int o = (wc * 32 + jj * 16 + lr) * 64 + kb;
      o ^= ((o >> 7) & 3) << 4;
      bf[jj] = *(const bf16x8*)((const char*)(buf + 8192) + o);
    }
    if (t + 2 < NT) STG2_A(t + 2);
    BAR();
    WAITL();
    __builtin_amdgcn_s_setprio(1);
#pragma unroll
    for (int i = 0; i < 4; ++i)
#pragma unroll
      for (int jj = 0; jj < 2; ++jj)
        acc[i][jj] = __builtin_amdgcn_mfma_f32_16x16x32_bf16(af[i], bf[jj], acc[i][jj], 0, 0, 0);
    __builtin_amdgcn_s_setprio(0);
    BAR();
    // -------- phase 1: i4-7 x j0-1 --------
#pragma unroll
    for (int i = 0; i < 4; ++i) {
      int o = (wr * 128 + (i + 4) * 16 + lr) * 64 + kb;
      o ^= ((o >> 7) & 3) << 4;
      af[i] = *(const bf16x8*)((const char*)buf + o);
    }
    if (t + 2 < NT) STG2_B(t + 2);
    BAR();
    WAITL();
    __builtin_amdgcn_s_setprio(1);
#pragma unroll
    for (int i = 0; i < 4; ++i)
#pragma unroll
      for (int jj = 0; jj < 2; ++jj)
        acc[i + 4][jj] = __builtin_amdgcn_mfma_f32_16x16x32_bf16(af[i], bf[jj], acc[i + 4][jj], 0, 0, 0);
    __builtin_amdgcn_s_setprio(0);
    if (t + 2 < NT) { WAITV(3); }
    else if (t == NT - 2) { WAITV(0); }
    BAR();
  }

  // ---- epilogue: per-wave [16][36] transpose tiles -> coalesced nt stores ----
  float* Tw = (float*)&lds[0][0] + wave * 1152;
  f32x4 bv4 = *(const f32x4*)&bias[n0 + wc * 32 + ((lane & 7) << 2)];
#pragma unroll
  for (int i = 0; i < 8; ++i) {
    float* T = Tw + (i & 1) * 576;
#pragma unroll
    for (int jj = 0; jj < 2; ++jj)
#pragma unroll
      for (int qq = 0; qq < 4; ++qq)
        T[(lq * 4 + qq) * 36 + jj * 16 + lr] = acc[i][jj][qq];
#pragma unroll
    for (int s = 0; s < 2; ++s) {
      f32x4 v = *(const f32x4*)&T[(s * 8 + (lane >> 3)) * 36 + ((lane & 7) << 2)];
      v += bv4;
      long row = m0 + wr * 128 + i * 16 + s * 8 + (lane >> 3);
      __builtin_nontemporal_store(v, (f32x4*)&C[row * ldc + n0 + wc * 32 + ((lane & 7) << 2)]);
    }
  }
#undef STG2_A
#undef STG2_B
}

extern "C" void kernel_launch(void* const* d_in, const int* in_sizes, int n_in,
                              void* d_out, int out_size, void* d_ws, size_t ws_size,
                              hipStream_t stream) {
  const int*   ids  = (const int*)d_in[0];
  const float* c1   = (const float*)d_in[1];
  const float* h1   = (const float*)d_in[2];
  const float* c2   = (const float*)d_in[3];
  const float* h2   = (const float*)d_in[4];
  const float* embW = (const float*)d_in[5];
  const float* W1   = (const float*)d_in[6];
  const float* b1   = (const float*)d_in[7];
  const float* W2   = (const float*)d_in[8];
  const float* b2   = (const float*)d_in[9];
  const float* decW = (const float*)d_in[10];
  const float* decb = (const float*)d_in[11];
  float* out = (float*)d_out;

  char* ws = (char*)d_ws;
  unsigned short* A    = (unsigned short*)(ws);
  unsigned short* z    = (unsigned short*)(ws + 16777216L);
  unsigned short* cWb1 = (unsigned short*)(ws + 44040192L);
  unsigned short* cWb2 = (unsigned short*)(ws + 69206016L);
  unsigned short* dWb  = (unsigned short*)(ws + 44040192L);  // overlaps dead cWb*

  float* out_dec = out;
  float* out_c1  = out + 131072000L;
  float* out_h1  = out_c1 + 4194304L;
  float* out_c2  = out_h1 + 4194304L;
  float* out_h2  = out_c2 + 4194304L;

  dim3 blk(256), gblk(512);
  dim3 gcell(12, 16);

  // ---- fused pre: convW1 + convW2 + gather ----
  fused_pre<<<dim3(28672), blk, 0, stream>>>(W1, cWb1, W2, cWb2, ids, embW, h1, A);

  // ---- cell 1 ----
  gemm8p<true><<<gcell, gblk, 0, stream>>>(A, 2048, cWb1, 2048, b1, z, 3072, 2048);
  act_gate<<<dim3(4096), blk, 0, stream>>>(z, c1, out_c1, A + 1024, 0, nullptr, nullptr,
                                           nullptr, nullptr, 0, 0);
  gemm8p<true><<<gcell, gblk, 0, stream>>>(A, 2048, cWb1 + 3072L * 2048, 2048, b1 + 3072, z, 3072, 2048);
  act_gate<<<dim3(4096), blk, 0, stream>>>(z, h1, out_h1, A, 1, h2, A + 1024,
                                           nullptr, nullptr, 0, 0);

  // ---- cell 2 ----
  gemm8p<true><<<gcell, gblk, 0, stream>>>(A, 2048, cWb2, 2048, b2, z, 3072, 2048);
  act_gate<<<dim3(4096), blk, 0, stream>>>(z, c2, out_c2, A + 1024, 0, nullptr, nullptr,
                                           nullptr, nullptr, 0, 0);
  gemm8p<true><<<gcell, gblk, 0, stream>>>(A, 2048, cWb2 + 3072L * 2048, 2048, b2 + 3072, z, 3072, 2048);
  // act4 fused with decoder weight conversion (32000 conv blocks + 4096 act rows)
  act_gate<<<dim3(36096), blk, 0, stream>>>(z, h2, out_h2, A, 1, nullptr, nullptr,
                                            decW, dWb, 32000, 32000L * 1024 / 4);

  // ---- decoder: BM=256,BN=128 ring-3, 2 blocks/CU ----
  {
    dim3 g(250, 16);                           // 4000 blocks (%8==0)
    gemm2b<<<g, gblk, 0, stream>>>(A, 2048, dWb, 1024, decb, out_dec, 32000, 1024);
  }
}

// Round 8
// 632.163 us; speedup vs baseline: 1.0538x; 1.0538x over previous
//
#include <hip/hip_runtime.h>

// RevRNN forward on MI355X — round 8:
//  * decoder: REVERT to r6-proven gemm8p 256x256 (gemm2b regressed: +LLC traffic).
//  * cells: NEW gemm8n — BM=256, BN=192, BK=64 -> grid 16x16 = 256 blocks =
//    100% CU coverage (was 192/256 = 75%). Same 8-phase vmcnt ledger; B subs
//    12KB staged with a duplicate-write trick to keep per-wave vmcnt uniform.
//  * fusions kept from r7 (pre: convW1+convW2+gather; act4+convDec).
//
// ws layout (bytes):
//   A    @ 0         [4096][2048] bf16  16.8 MB
//   z    @ 16777216  [4096][3072] bf16  25.2 MB (live until act4)
//   cWb1 @ 44040192  [6144][2048] bf16  25.2 MB (dead after cell1 gemm2)
//   cWb2 @ 69206016  [6144][2048] bf16  25.2 MB (dead after cell2 gemm2)
//   dWb  @ 44040192  [32000][1024] bf16 65.5 MB (written at act4 over dead cWb1)

typedef __attribute__((ext_vector_type(4))) float f32x4;
typedef __attribute__((ext_vector_type(8))) short bf16x8;
typedef __attribute__((ext_vector_type(4))) unsigned short u16x4;

__device__ __forceinline__ unsigned short f2bf(float x) {
  unsigned u = __float_as_uint(x);
  return (unsigned short)((u + 0x7fffu + ((u >> 16) & 1u)) >> 16);  // RNE
}
__device__ __forceinline__ float bf2f(unsigned short h) {
  return __uint_as_float(((unsigned)h) << 16);
}
__device__ __forceinline__ u16x4 cvt4v(f32x4 v) {
  u16x4 h;
  h[0] = f2bf(v[0]); h[1] = f2bf(v[1]); h[2] = f2bf(v[2]); h[3] = f2bf(v[3]);
  return h;
}
__device__ __forceinline__ float sigf(float x) { return 1.0f / (1.0f + expf(-x)); }

__device__ __forceinline__ void conv_chunk(const float* __restrict__ src,
                                           unsigned short* __restrict__ dst,
                                           long i, long n4) {
  if (i >= n4) return;
  f32x4 v = __builtin_nontemporal_load(reinterpret_cast<const f32x4*>(src) + i);
  reinterpret_cast<u16x4*>(dst)[i] = cvt4v(v);
}

// ---- fused: convW1 + convW2 + gather_cat ----
__global__ void fused_pre(const float* __restrict__ W1, unsigned short* __restrict__ cWb1,
                          const float* __restrict__ W2, unsigned short* __restrict__ cWb2,
                          const int* __restrict__ ids, const float* __restrict__ embW,
                          const float* __restrict__ h1, unsigned short* __restrict__ A) {
  const long n4 = 6L * 1024 * 2048 / 4;
  int b = blockIdx.x;
  int t = threadIdx.x;
  if (b < 12288) {
    conv_chunk(W1, cWb1, (long)b * 256 + t, n4);
  } else if (b < 24576) {
    conv_chunk(W2, cWb2, (long)(b - 12288) * 256 + t, n4);
  } else {
    int r = b - 24576;
    long erow = (long)ids[r] * 1024;
    f32x4 e = reinterpret_cast<const f32x4*>(embW + erow)[t];
    f32x4 h = reinterpret_cast<const f32x4*>(h1 + (long)r * 1024)[t];
    reinterpret_cast<u16x4*>(A + (long)r * 2048)[t] = cvt4v(e);
    reinterpret_cast<u16x4*>(A + (long)r * 2048 + 1024)[t] = cvt4v(h);
  }
}

// ---- gate activation (z bf16); optional fused decoder-weight conversion ----
__global__ void act_gate(const unsigned short* __restrict__ z, const float* __restrict__ prev,
                         float* __restrict__ outf, unsigned short* __restrict__ obf,
                         int swap01,
                         const float* __restrict__ xsrc, unsigned short* __restrict__ xbf,
                         const float* __restrict__ cvsrc, unsigned short* __restrict__ cvdst,
                         long cvblocks, long cvn4) {
  long b = blockIdx.x;
  int t = threadIdx.x;
  if (b < cvblocks) {
    conv_chunk(cvsrc, cvdst, b * 256 + t, cvn4);
    return;
  }
  b -= cvblocks;
  long zb = b * 3072;
  u16x4 u0 = reinterpret_cast<const u16x4*>(z + zb)[t];
  u16x4 u1 = reinterpret_cast<const u16x4*>(z + zb + 1024)[t];
  u16x4 u2 = reinterpret_cast<const u16x4*>(z + zb + 2048)[t];
  if (swap01) { u16x4 tmp = u0; u0 = u1; u1 = tmp; }
  f32x4 p = reinterpret_cast<const f32x4*>(prev + b * 1024)[t];
  f32x4 o;
#pragma unroll
  for (int k = 0; k < 4; ++k)
    o[k] = (sigf(bf2f(u0[k])) * p[k] + sigf(bf2f(u1[k])) * tanhf(bf2f(u2[k]))) * 0.5f;
  __builtin_nontemporal_store(o, reinterpret_cast<f32x4*>(outf + b * 1024) + t);
  reinterpret_cast<u16x4*>(obf + b * 2048)[t] = cvt4v(o);
  if (xsrc) {
    f32x4 x = reinterpret_cast<const f32x4*>(xsrc + b * 1024)[t];
    reinterpret_cast<u16x4*>(xbf + b * 2048)[t] = cvt4v(x);
  }
}

// ---- async global->LDS 16B ----
__device__ __forceinline__ void load16(const void* g, void* l) {
  __builtin_amdgcn_global_load_lds((const __attribute__((address_space(1))) unsigned int*)g,
                                   (__attribute__((address_space(3))) unsigned int*)l,
                                   16, 0, 0);
}

#define WAITV(n) do { asm volatile("s_waitcnt vmcnt(" #n ")" ::: "memory");      \
    __builtin_amdgcn_sched_barrier(0); } while (0)
#define WAITL() do { asm volatile("s_waitcnt lgkmcnt(0)" ::: "memory");          \
    __builtin_amdgcn_sched_barrier(0); } while (0)
#define BAR() __builtin_amdgcn_s_barrier()

// ---- shared bijective 2D XCD super-block mapping (nwg % 8 == 0) ----
__device__ __forceinline__ void superblock(int gx, int gy, int& bx, int& by) {
  const int nwg = gx * gy;
  int bid = blockIdx.y * gx + blockIdx.x;
  const int q = nwg >> 3;
  const int x = bid & 7, j = bid >> 3;
  const int p = x >> 1, half = x & 1;
  const int w0 = (gx + 1) >> 1;
  int byl;
  if ((w0 << 2) == q) {
    bx = half * w0 + (j >> 2);
    byl = j & 3;
  } else {
    if (j < q - 2) { bx = (half ? w0 : 0) + (j >> 2); byl = j & 3; }
    else { bx = w0 - 1; byl = (half ? 2 : 0) + (j - (q - 2)); }
  }
  by = p * 4 + byl;
}

// ================= 8-phase 256x256 bf16 GEMM (decoder; r6-verified) =================
__global__ __launch_bounds__(512, 2) void gemm8p(
    const unsigned short* __restrict__ A, int lda,
    const unsigned short* __restrict__ B, int ldb,
    const float* __restrict__ bias, float* __restrict__ C, long ldc, int K) {
  __shared__ unsigned short lds[2][4][8192];  // 128 KiB

  int bx, by;
  superblock(gridDim.x, gridDim.y, bx, by);
  const long m0 = (long)by * 256;
  const long n0 = (long)bx * 256;

  const int tid = threadIdx.x;
  const int lane = tid & 63;
  const int wave = tid >> 6;
  const int wr = wave >> 2;
  const int wc = wave & 3;
  const int lr = lane & 15;
  const int lq = lane >> 4;
  const int kb = lq * 16;

  const int o0 = tid * 16, o1 = tid * 16 + 8192;
  const int q0 = o0 ^ (((o0 >> 7) & 3) << 4);
  const int q1 = o1 ^ (((o1 >> 7) & 3) << 4);
  const char* pa0 = (const char*)(A + (m0 + (q0 >> 6)) * lda) + (q0 & 63);
  const char* pa1 = (const char*)(A + (m0 + (q1 >> 6)) * lda) + (q1 & 63);
  const char* pb0 = (const char*)(B + (n0 + (q0 >> 6)) * ldb) + (q0 & 63);
  const char* pb1 = (const char*)(B + (n0 + (q1 >> 6)) * ldb) + (q1 & 63);

  const int NT = K >> 6;

#define STG_A(t_, kh_) do { int ko = ((t_) << 7) + ((kh_) << 6);                 \
    char* d = (char*)&lds[(t_) & 1][(kh_) ? 2 : 0][0];                           \
    load16(pa0 + ko, d + o0); load16(pa1 + ko, d + o1); } while (0)
#define STG_B(t_, kh_) do { int ko = ((t_) << 7) + ((kh_) << 6);                 \
    char* d = (char*)&lds[(t_) & 1][(kh_) ? 3 : 1][0];                           \
    load16(pb0 + ko, d + o0); load16(pb1 + ko, d + o1); } while (0)

  f32x4 acc[8][4] = {};
  bf16x8 af[4], bf[4];

  STG_B(0, 0); STG_A(0, 0); STG_B(0, 1); STG_A(0, 1);
  STG_B(1, 0); STG_A(1, 0); STG_B(1, 1);
  WAITV(6);
  BAR();

  for (int t = 0; t < NT; ++t) {
    const int cur = t & 1;
    // phase 0
#pragma unroll
    for (int i = 0; i < 4; ++i) {
      int o = (wr * 128 + i * 16 + lr) * 64 + kb;
      o ^= ((o >> 7) & 3) << 4;
      af[i] = *(const bf16x8*)((const char*)&lds[cur][0][0] + o);
    }
#pragma unroll
    for (int jj = 0; jj < 4; ++jj) {
      int o = (wc * 64 + jj * 16 + lr) * 64 + kb;
      o ^= ((o >> 7) & 3) << 4;
      bf[jj] = *(const bf16x8*)((const char*)&lds[cur][1][0] + o);
    }
    if (t + 1 < NT) STG_A(t + 1, 1);
    BAR();
    WAITL();
    __builtin_amdgcn_s_setprio(1);
#pragma unroll
    for (int i = 0; i < 4; ++i)
#pragma unroll
      for (int jj = 0; jj < 4; ++jj)
        acc[i][jj] = __builtin_amdgcn_mfma_f32_16x16x32_bf16(af[i], bf[jj], acc[i][jj], 0, 0, 0);
    __builtin_amdgcn_s_setprio(0);
    BAR();
    // phase 1
#pragma unroll
    for (int i = 0; i < 4; ++i) {
      int o = (wr * 128 + (i + 4) * 16 + lr) * 64 + kb;
      o ^= ((o >> 7) & 3) << 4;
      af[i] = *(const bf16x8*)((const char*)&lds[cur][0][0] + o);
    }
    if (t + 2 < NT) STG_B(t + 2, 0);
    BAR();
    WAITL();
    __builtin_amdgcn_s_setprio(1);
#pragma unroll
    for (int i = 0; i < 4; ++i)
#pragma unroll
      for (int jj = 0; jj < 4; ++jj)
        acc[i + 4][jj] = __builtin_amdgcn_mfma_f32_16x16x32_bf16(af[i], bf[jj], acc[i + 4][jj], 0, 0, 0);
    __builtin_amdgcn_s_setprio(0);
    BAR();
    // phase 2
#pragma unroll
    for (int i = 0; i < 4; ++i) {
      int o = (wr * 128 + i * 16 + lr) * 64 + kb;
      o ^= ((o >> 7) & 3) << 4;
      af[i] = *(const bf16x8*)((const char*)&lds[cur][2][0] + o);
    }
#pragma unroll
    for (int jj = 0; jj < 4; ++jj) {
      int o = (wc * 64 + jj * 16 + lr) * 64 + kb;
      o ^= ((o >> 7) & 3) << 4;
      bf[jj] = *(const bf16x8*)((const char*)&lds[cur][3][0] + o);
    }
    if (t + 2 < NT) STG_A(t + 2, 0);
    BAR();
    WAITL();
    __builtin_amdgcn_s_setprio(1);
#pragma unroll
    for (int i = 0; i < 4; ++i)
#pragma unroll
      for (int jj = 0; jj < 4; ++jj)
        acc[i][jj] = __builtin_amdgcn_mfma_f32_16x16x32_bf16(af[i], bf[jj], acc[i][jj], 0, 0, 0);
    __builtin_amdgcn_s_setprio(0);
    BAR();
    // phase 3
#pragma unroll
    for (int i = 0; i < 4; ++i) {
      int o = (wr * 128 + (i + 4) * 16 + lr) * 64 + kb;
      o ^= ((o >> 7) & 3) << 4;
      af[i] = *(const bf16x8*)((const char*)&lds[cur][2][0] + o);
    }
    if (t + 2 < NT) STG_B(t + 2, 1);
    BAR();
    WAITL();
    __builtin_amdgcn_s_setprio(1);
#pragma unroll
    for (int i = 0; i < 4; ++i)
#pragma unroll
      for (int jj = 0; jj < 4; ++jj)
        acc[i + 4][jj] = __builtin_amdgcn_mfma_f32_16x16x32_bf16(af[i], bf[jj], acc[i + 4][jj], 0, 0, 0);
    __builtin_amdgcn_s_setprio(0);
    if (t <= NT - 3) { WAITV(6); }
    else if (t == NT - 2) { WAITV(0); }
    BAR();
  }

  float* Tw = (float*)&lds[0][0][0] + wave * 2176;   // two [16][68] f32 tiles
  f32x4 bv4 = *(const f32x4*)&bias[n0 + wc * 64 + lr * 4];
#pragma unroll
  for (int i = 0; i < 8; ++i) {
    float* T = Tw + (i & 1) * 1088;
#pragma unroll
    for (int jj = 0; jj < 4; ++jj)
#pragma unroll
      for (int qq = 0; qq < 4; ++qq)
        T[(lq * 4 + qq) * 68 + jj * 16 + lr] = acc[i][jj][qq];
#pragma unroll
    for (int s = 0; s < 4; ++s) {
      f32x4 v = *(const f32x4*)&T[(s * 4 + lq) * 68 + lr * 4];
      v += bv4;
      long row = m0 + wr * 128 + i * 16 + s * 4 + lq;
      __builtin_nontemporal_store(v, (f32x4*)&C[row * ldc + n0 + wc * 64 + lr * 4]);
    }
  }
#undef STG_A
#undef STG_B
}

// ============ 8-phase 256x192 bf16 GEMM (cells; grid 16x16 = 256 blocks) ============
// LDS per buf: A_k0 16KB @0, B_k0 12KB @16384, A_k1 16KB @28672, B_k1 12KB @45056
// (56KB/buf, 112KB total). B staged with duplicate-write trick (waves 4-7 mirror
// waves 0-3's upper 4KB) so every wave issues 2 loads per STG -> vmcnt ledger
// identical to gemm8p (verified r3-r7). Output bf16 (z).
__global__ __launch_bounds__(512, 2) void gemm8n(
    const unsigned short* __restrict__ A, int lda,
    const unsigned short* __restrict__ B, int ldb,
    const float* __restrict__ bias, unsigned short* __restrict__ C, long ldc, int K) {
  __shared__ unsigned short lds[57344];  // 112 KiB

  int bx, by;
  superblock(gridDim.x, gridDim.y, bx, by);
  const long m0 = (long)by * 256;
  const long n0 = (long)bx * 192;

  const int tid = threadIdx.x;
  const int lane = tid & 63;
  const int wave = tid >> 6;
  const int wr = wave >> 2;                    // 0..1 (128 rows)
  const int wc = wave & 3;                     // 0..3 (48 cols)
  const int lr = lane & 15;
  const int lq = lane >> 4;
  const int kb = lq * 16;

  // A staging: 16KB sub = 2x load16/thread
  const int o0 = tid * 16, o1 = tid * 16 + 8192;
  const int q0 = o0 ^ (((o0 >> 7) & 3) << 4);
  const int q1 = o1 ^ (((o1 >> 7) & 3) << 4);
  const char* pa0 = (const char*)(A + (m0 + (q0 >> 6)) * lda) + (q0 & 63);
  const char* pa1 = (const char*)(A + (m0 + (q1 >> 6)) * lda) + (q1 & 63);
  // B staging: 12KB sub = load16 all threads (8KB) + duplicated upper 4KB
  const int oB1 = 8192 + (tid & 255) * 16;     // waves 4-7 mirror waves 0-3
  const int qB1 = oB1 ^ (((oB1 >> 7) & 3) << 4);
  const char* pb0 = (const char*)(B + (n0 + (q0 >> 6)) * ldb) + (q0 & 63);
  const char* pb1 = (const char*)(B + (n0 + (qB1 >> 6)) * ldb) + (qB1 & 63);

  const int NT = K >> 6;

#define STG_A(t_, kh_) do { int ko = ((t_) << 7) + ((kh_) << 6);                 \
    char* d = (char*)&lds[0] + ((t_) & 1) * 57344/2*2/2*1;                       \
    d = (char*)&lds[0] + ((t_) & 1) * 57344 / 2 * 0 + ((t_) & 1) * 57344;        \
    d = (char*)&lds[0] + ((t_) & 1) * 57344; /* unreachable-safe recompute */    \
    (void)d; char* dd = (char*)&lds[0] + ((t_) & 1) * 57344 / 2;                 \
    (void)dd; char* base = (char*)&lds[0] + ((t_) & 1) * 28672 * 2;              \
    char* dst = base + ((kh_) ? 28672 : 0);                                      \
    load16(pa0 + ko, dst + o0); load16(pa1 + ko, dst + o1); } while (0)
#define STG_B(t_, kh_) do { int ko = ((t_) << 7) + ((kh_) << 6);                 \
    char* base = (char*)&lds[0] + ((t_) & 1) * 57344;                            \
    char* dst = base + ((kh_) ? 45056 : 16384);                                  \
    load16(pb0 + ko, dst + o0); load16(pb1 + ko, dst + oB1); } while (0)

  f32x4 acc[8][3] = {};
  bf16x8 af[4], bf[3];

  STG_B(0, 0); STG_A(0, 0); STG_B(0, 1); STG_A(0, 1);
  STG_B(1, 0); STG_A(1, 0); STG_B(1, 1);
  WAITV(6);
  BAR();

  for (int t = 0; t < NT; ++t) {
    const char* base = (const char*)&lds[0] + (t & 1) * 57344;
    // phase 0: kh0, i0-3 x j0-2
#pragma unroll
    for (int i = 0; i < 4; ++i) {
      int o = (wr * 128 + i * 16 + lr) * 64 + kb;
      o ^= ((o >> 7) & 3) << 4;
      af[i] = *(const bf16x8*)(base + o);
    }
#pragma unroll
    for (int jj = 0; jj < 3; ++jj) {
      int o = (wc * 48 + jj * 16 + lr) * 64 + kb;
      o ^= ((o >> 7) & 3) << 4;
      bf[jj] = *(const bf16x8*)(base + 16384 + o);
    }
    if (t + 1 < NT) STG_A(t + 1, 1);
    BAR();
    WAITL();
    __builtin_amdgcn_s_setprio(1);
#pragma unroll
    for (int i = 0; i < 4; ++i)
#pragma unroll
      for (int jj = 0; jj < 3; ++jj)
        acc[i][jj] = __builtin_amdgcn_mfma_f32_16x16x32_bf16(af[i], bf[jj], acc[i][jj], 0, 0, 0);
    __builtin_amdgcn_s_setprio(0);
    BAR();
    // phase 1: kh0, i4-7
#pragma unroll
    for (int i = 0; i < 4; ++i) {
      int o = (wr * 128 + (i + 4) * 16 + lr) * 64 + kb;
      o ^= ((o >> 7) & 3) << 4;
      af[i] = *(const bf16x8*)(base + o);
    }
    if (t + 2 < NT) STG_B(t + 2, 0);
    BAR();
    WAITL();
    __builtin_amdgcn_s_setprio(1);
#pragma unroll
    for (int i = 0; i < 4; ++i)
#pragma unroll
      for (int jj = 0; jj < 3; ++jj)
        acc[i + 4][jj] = __builtin_amdgcn_mfma_f32_16x16x32_bf16(af[i], bf[jj], acc[i + 4][jj], 0, 0, 0);
    __builtin_amdgcn_s_setprio(0);
    BAR();
    // phase 2: kh1, i0-3 x j0-2
#pragma unroll
    for (int i = 0; i < 4; ++i) {
      int o = (wr * 128 + i * 16 + lr) * 64 + kb;
      o ^= ((o >> 7) & 3) << 4;
      af[i] = *(const bf16x8*)(base + 28672 + o);
    }
#pragma unroll
    for (int jj = 0; jj < 3; ++jj) {
      int o = (wc * 48 + jj * 16 + lr) * 64 + kb;
      o ^= ((o >> 7) & 3) << 4;
      bf[jj] = *(const bf16x8*)(base + 45056 + o);
    }
    if (t + 2 < NT) STG_A(t + 2, 0);
    BAR();
    WAITL();
    __builtin_amdgcn_s_setprio(1);
#pragma unroll
    for (int i = 0; i < 4; ++i)
#pragma unroll
      for (int jj = 0; jj < 3; ++jj)
        acc[i][jj] = __builtin_amdgcn_mfma_f32_16x16x32_bf16(af[i], bf[jj], acc[i][jj], 0, 0, 0);
    __builtin_amdgcn_s_setprio(0);
    BAR();
    // phase 3: kh1, i4-7
#pragma unroll
    for (int i = 0; i < 4; ++i) {
      int o = (wr * 128 + (i + 4) * 16 + lr) * 64 + kb;
      o ^= ((o >> 7) & 3) << 4;
      af[i] = *(const bf16x8*)(base + 28672 + o);
    }
    if (t + 2 < NT) STG_B(t + 2, 1);
    BAR();
    WAITL();
    __builtin_amdgcn_s_setprio(1);
#pragma unroll
    for (int i = 0; i < 4; ++i)
#pragma unroll
      for (int jj = 0; jj < 3; ++jj)
        acc[i + 4][jj] = __builtin_amdgcn_mfma_f32_16x16x32_bf16(af[i], bf[jj], acc[i + 4][jj], 0, 0, 0);
    __builtin_amdgcn_s_setprio(0);
    if (t <= NT - 3) { WAITV(6); }
    else if (t == NT - 2) { WAITV(0); }
    BAR();
  }

  // epilogue: per-wave [16][52] f32 transpose tiles (x2) -> u16x4 stores
  float* Tw = (float*)&lds[0] + wave * 1664;
  f32x4 bv4 = *(const f32x4*)&bias[n0 + wc * 48 + lr * 4];  // used only when lr<12
#pragma unroll
  for (int i = 0; i < 8; ++i) {
    float* T = Tw + (i & 1) * 832;
#pragma unroll
    for (int jj = 0; jj < 3; ++jj)
#pragma unroll
      for (int qq = 0; qq < 4; ++qq)
        T[(lq * 4 + qq) * 52 + jj * 16 + lr] = acc[i][jj][qq];
#pragma unroll
    for (int s = 0; s < 4; ++s) {
      if (lr < 12) {
        f32x4 v = *(const f32x4*)&T[(s * 4 + lq) * 52 + lr * 4];
        v += bv4;
        long row = m0 + wr * 128 + i * 16 + s * 4 + lq;
        *(u16x4*)&C[row * ldc + n0 + wc * 48 + lr * 4] = cvt4v(v);
      }
    }
  }
#undef STG_A
#undef STG_B
}

extern "C" void kernel_launch(void* const* d_in, const int* in_sizes, int n_in,
                              void* d_out, int out_size, void* d_ws, size_t ws_size,
                              hipStream_t stream) {
  const int*   ids  = (const int*)d_in[0];
  const float* c1   = (const float*)d_in[1];
  const float* h1   = (const float*)d_in[2];
  const float* c2   = (const float*)d_in[3];
  const float* h2   = (const float*)d_in[4];
  const float* embW = (const float*)d_in[5];
  const float* W1   = (const float*)d_in[6];
  const float* b1   = (const float*)d_in[7];
  const float* W2   = (const float*)d_in[8];
  const float* b2   = (const float*)d_in[9];
  const float* decW = (const float*)d_in[10];
  const float* decb = (const float*)d_in[11];
  float* out = (float*)d_out;

  char* ws = (char*)d_ws;
  unsigned short* A    = (unsigned short*)(ws);
  unsigned short* z    = (unsigned short*)(ws + 16777216L);
  unsigned short* cWb1 = (unsigned short*)(ws + 44040192L);
  unsigned short* cWb2 = (unsigned short*)(ws + 69206016L);
  unsigned short* dWb  = (unsigned short*)(ws + 44040192L);  // overlaps dead cWb1

  float* out_dec = out;
  float* out_c1  = out + 131072000L;
  float* out_h1  = out_c1 + 4194304L;
  float* out_c2  = out_h1 + 4194304L;
  float* out_h2  = out_c2 + 4194304L;

  dim3 blk(256), gblk(512);
  dim3 gcell(16, 16);                          // N=3072/192, M=4096/256 -> 256 blocks

  // ---- fused pre: convW1 + convW2 + gather ----
  fused_pre<<<dim3(28672), blk, 0, stream>>>(W1, cWb1, W2, cWb2, ids, embW, h1, A);

  // ---- cell 1 ----
  gemm8n<<<gcell, gblk, 0, stream>>>(A, 2048, cWb1, 2048, b1, z, 3072, 2048);
  act_gate<<<dim3(4096), blk, 0, stream>>>(z, c1, out_c1, A + 1024, 0, nullptr, nullptr,
                                           nullptr, nullptr, 0, 0);
  gemm8n<<<gcell, gblk, 0, stream>>>(A, 2048, cWb1 + 3072L * 2048, 2048, b1 + 3072, z, 3072, 2048);
  act_gate<<<dim3(4096), blk, 0, stream>>>(z, h1, out_h1, A, 1, h2, A + 1024,
                                           nullptr, nullptr, 0, 0);

  // ---- cell 2 ----
  gemm8n<<<gcell, gblk, 0, stream>>>(A, 2048, cWb2, 2048, b2, z, 3072, 2048);
  act_gate<<<dim3(4096), blk, 0, stream>>>(z, c2, out_c2, A + 1024, 0, nullptr, nullptr,
                                           nullptr, nullptr, 0, 0);
  gemm8n<<<gcell, gblk, 0, stream>>>(A, 2048, cWb2 + 3072L * 2048, 2048, b2 + 3072, z, 3072, 2048);
  // act4 fused with decoder weight conversion
  act_gate<<<dim3(36096), blk, 0, stream>>>(z, h2, out_h2, A, 1, nullptr, nullptr,
                                            decW, dWb, 32000, 32000L * 1024 / 4);

  // ---- decoder: r6-proven 256x256 ----
  {
    dim3 g(125, 16);                           // 2000 blocks (%8==0)
    gemm8p<<<g, gblk, 0, stream>>>(A, 2048, dWb, 1024, decb, out_dec, 32000, 1024);
  }
}

// Round 9
// 608.471 us; speedup vs baseline: 1.0948x; 1.0389x over previous
//
#include <hip/hip_runtime.h>

// RevRNN forward on MI355X — round 9: act fused into cell-GEMM epilogue.
//  * cells: gemm8f — BM=256, 3-gate tiling (N=1024 cols x 3 gates, B panel =
//    192 rows = gemm8n's verified 12KB dup-write staging). Epilogue computes
//    the gate nonlinearity directly from acc (fp32 z, never materialized).
//  * A-buffer ping-pong (no kernel reads+writes the same buffer):
//      pre:   A0=[emb|h1], A1=[emb|-], A2=[-|h2]
//      g1(A0)-> c1n: out_c1 + A1[:,1024:]      (A1=[emb|c1n])
//      g2(A1)-> h1n: out_h1 + A2[:,0:] + A0[:,0:]  (A2=[h1n|h2], A0=[h1n|-])
//      g3(A2)-> c2n: out_c2 + A0[:,1024:]      (A0=[h1n|c2n])
//      g4(A0)-> h2n: out_h2 + A4 packed (lda 1024, @A1 region)
//  * decoder: r8-proven gemm8p (lda=1024 A) after standalone convDec.
//
// ws layout (bytes), peak 115.9 MB:
//   A0 @0          16.8 MB   A1 @16777216  16.8 MB (A4 packed reuses this)
//   A2 @33554432   16.8 MB
//   cWb1 @50331648 25.2 MB (dead after g2)   cWb2 @75497472 25.2 MB (dead after g4)
//   dWb @50331648  65.5 MB (convDec runs after g4, over dead cWb1/cWb2)

typedef __attribute__((ext_vector_type(4))) float f32x4;
typedef __attribute__((ext_vector_type(8))) short bf16x8;
typedef __attribute__((ext_vector_type(4))) unsigned short u16x4;

__device__ __forceinline__ unsigned short f2bf(float x) {
  unsigned u = __float_as_uint(x);
  return (unsigned short)((u + 0x7fffu + ((u >> 16) & 1u)) >> 16);  // RNE
}
__device__ __forceinline__ u16x4 cvt4v(f32x4 v) {
  u16x4 h;
  h[0] = f2bf(v[0]); h[1] = f2bf(v[1]); h[2] = f2bf(v[2]); h[3] = f2bf(v[3]);
  return h;
}
__device__ __forceinline__ float sigf(float x) { return 1.0f / (1.0f + expf(-x)); }

__device__ __forceinline__ void conv_chunk(const float* __restrict__ src,
                                           unsigned short* __restrict__ dst,
                                           long i, long n4) {
  if (i >= n4) return;
  f32x4 v = __builtin_nontemporal_load(reinterpret_cast<const f32x4*>(src) + i);
  reinterpret_cast<u16x4*>(dst)[i] = cvt4v(v);
}

// ---- fp32 -> bf16 streaming conversion (decoder weights) ----
__global__ void convbf(const float* __restrict__ src, unsigned short* __restrict__ dst, long n4) {
  long i = (long)blockIdx.x * blockDim.x + threadIdx.x;
  if (i >= n4) return;
  conv_chunk(src, dst, i, n4);
}

// ---- fused: convW1 + convW2 + gather/seed A-buffers ----
__global__ void fused_pre(const float* __restrict__ W1, unsigned short* __restrict__ cWb1,
                          const float* __restrict__ W2, unsigned short* __restrict__ cWb2,
                          const int* __restrict__ ids, const float* __restrict__ embW,
                          const float* __restrict__ h1, const float* __restrict__ h2,
                          unsigned short* __restrict__ A0, unsigned short* __restrict__ A1,
                          unsigned short* __restrict__ A2) {
  const long n4 = 6L * 1024 * 2048 / 4;
  int b = blockIdx.x;
  int t = threadIdx.x;
  if (b < 12288) {
    conv_chunk(W1, cWb1, (long)b * 256 + t, n4);
  } else if (b < 24576) {
    conv_chunk(W2, cWb2, (long)(b - 12288) * 256 + t, n4);
  } else {
    int r = b - 24576;
    long erow = (long)ids[r] * 1024;
    u16x4 e = cvt4v(reinterpret_cast<const f32x4*>(embW + erow)[t]);
    reinterpret_cast<u16x4*>(A0 + (long)r * 2048)[t] = e;
    reinterpret_cast<u16x4*>(A1 + (long)r * 2048)[t] = e;
    reinterpret_cast<u16x4*>(A0 + (long)r * 2048 + 1024)[t] =
        cvt4v(reinterpret_cast<const f32x4*>(h1 + (long)r * 1024)[t]);
    reinterpret_cast<u16x4*>(A2 + (long)r * 2048 + 1024)[t] =
        cvt4v(reinterpret_cast<const f32x4*>(h2 + (long)r * 1024)[t]);
  }
}

// ---- async global->LDS 16B ----
__device__ __forceinline__ void load16(const void* g, void* l) {
  __builtin_amdgcn_global_load_lds((const __attribute__((address_space(1))) unsigned int*)g,
                                   (__attribute__((address_space(3))) unsigned int*)l,
                                   16, 0, 0);
}

#define WAITV(n) do { asm volatile("s_waitcnt vmcnt(" #n ")" ::: "memory");      \
    __builtin_amdgcn_sched_barrier(0); } while (0)
#define WAITL() do { asm volatile("s_waitcnt lgkmcnt(0)" ::: "memory");          \
    __builtin_amdgcn_sched_barrier(0); } while (0)
#define BAR() __builtin_amdgcn_s_barrier()

// ---- bijective 2D XCD super-block mapping (nwg % 8 == 0) ----
__device__ __forceinline__ void superblock(int gx, int gy, int& bx, int& by) {
  const int nwg = gx * gy;
  int bid = blockIdx.y * gx + blockIdx.x;
  const int q = nwg >> 3;
  const int x = bid & 7, j = bid >> 3;
  const int p = x >> 1, half = x & 1;
  const int w0 = (gx + 1) >> 1;
  int byl;
  if ((w0 << 2) == q) {
    bx = half * w0 + (j >> 2);
    byl = j & 3;
  } else {
    if (j < q - 2) { bx = (half ? w0 : 0) + (j >> 2); byl = j & 3; }
    else { bx = w0 - 1; byl = (half ? 2 : 0) + (j - (q - 2)); }
  }
  by = p * 4 + byl;
}

// ========== fused cell GEMM+act: z[g] = A[M,2048]*W[g*1024+cols]^T + b ==========
// Grid (16,16) = 256 blocks. Block: 256 rows x 64 z-cols x 3 gates.
// LDS per buf: A_k0 16KB @0, B_k0 12KB @16384, A_k1 16KB @28672, B_k1 12KB @45056.
// B panel = 3 gates x 64 rows = 192 rows, staged exactly like gemm8n (r8-verified
// dup-write trick + same vmcnt ledger). Epilogue: o=(sig(zp)*prev+sig(zn)*tanh(z2))/2.
template <int SWAP>
__global__ __launch_bounds__(512, 2) void gemm8f(
    const unsigned short* __restrict__ A,
    const unsigned short* __restrict__ B,
    const float* __restrict__ bias,
    const float* __restrict__ prev,
    float* __restrict__ outf,
    unsigned short* __restrict__ obf1,
    unsigned short* __restrict__ obf2, long obld) {
  __shared__ unsigned short lds[57344];  // 112 KiB

  int bx, by;
  superblock(gridDim.x, gridDim.y, bx, by);   // gx=16 -> even path
  const long m0 = (long)by * 256;

  const int tid = threadIdx.x;
  const int lane = tid & 63;
  const int wave = tid >> 6;
  const int wr = wave >> 2;                    // 0..1 (128 rows)
  const int wc = wave & 3;                     // 0..3 (16 z-cols each)
  const int lr = lane & 15;
  const int lq = lane >> 4;
  const int kb = lq * 16;

  // A staging: 16KB sub = 2x load16/thread
  const int o0 = tid * 16, o1 = tid * 16 + 8192;
  const int q0 = o0 ^ (((o0 >> 7) & 3) << 4);
  const int q1 = o1 ^ (((o1 >> 7) & 3) << 4);
  const char* pa0 = (const char*)(A + (m0 + (q0 >> 6)) * 2048) + (q0 & 63);
  const char* pa1 = (const char*)(A + (m0 + (q1 >> 6)) * 2048) + (q1 & 63);
  // B staging: 12KB = 192 logical rows; lrow -> global row (lrow>>6)*1024+bx*64+(lrow&63)
  const int oB1 = 8192 + (tid & 255) * 16;     // waves 4-7 mirror waves 0-3
  const int qB1 = oB1 ^ (((oB1 >> 7) & 3) << 4);
  const int lrow0 = q0 >> 6, lrow1 = qB1 >> 6;
  const long grow0 = (long)(lrow0 >> 6) * 1024 + bx * 64 + (lrow0 & 63);
  const long grow1 = (long)(lrow1 >> 6) * 1024 + bx * 64 + (lrow1 & 63);
  const char* pb0 = (const char*)(B + grow0 * 2048) + (q0 & 63);
  const char* pb1 = (const char*)(B + grow1 * 2048) + (qB1 & 63);

  const int NT = 32;                           // K=2048, BK=64

#define STG_A(t_, kh_) do { int ko = ((t_) << 7) + ((kh_) << 6);                 \
    char* base = (char*)&lds[0] + ((t_) & 1) * 57344;                            \
    char* dst = base + ((kh_) ? 28672 : 0);                                      \
    load16(pa0 + ko, dst + o0); load16(pa1 + ko, dst + o1); } while (0)
#define STG_B(t_, kh_) do { int ko = ((t_) << 7) + ((kh_) << 6);                 \
    char* base = (char*)&lds[0] + ((t_) & 1) * 57344;                            \
    char* dst = base + ((kh_) ? 45056 : 16384);                                  \
    load16(pb0 + ko, dst + o0); load16(pb1 + ko, dst + oB1); } while (0)

  f32x4 acc[8][3] = {};
  bf16x8 af[4], bf[3];

  STG_B(0, 0); STG_A(0, 0); STG_B(0, 1); STG_A(0, 1);
  STG_B(1, 0); STG_A(1, 0); STG_B(1, 1);
  WAITV(6);
  BAR();

  for (int t = 0; t < NT; ++t) {
    const char* base = (const char*)&lds[0] + (t & 1) * 57344;
    // phase 0: kh0, i0-3 x g0-2
#pragma unroll
    for (int i = 0; i < 4; ++i) {
      int o = (wr * 128 + i * 16 + lr) * 64 + kb;
      o ^= ((o >> 7) & 3) << 4;
      af[i] = *(const bf16x8*)(base + o);
    }
#pragma unroll
    for (int g = 0; g < 3; ++g) {
      int o = (g * 64 + wc * 16 + lr) * 64 + kb;
      o ^= ((o >> 7) & 3) << 4;
      bf[g] = *(const bf16x8*)(base + 16384 + o);
    }
    if (t + 1 < NT) STG_A(t + 1, 1);
    BAR();
    WAITL();
    __builtin_amdgcn_s_setprio(1);
#pragma unroll
    for (int i = 0; i < 4; ++i)
#pragma unroll
      for (int g = 0; g < 3; ++g)
        acc[i][g] = __builtin_amdgcn_mfma_f32_16x16x32_bf16(af[i], bf[g], acc[i][g], 0, 0, 0);
    __builtin_amdgcn_s_setprio(0);
    BAR();
    // phase 1: kh0, i4-7
#pragma unroll
    for (int i = 0; i < 4; ++i) {
      int o = (wr * 128 + (i + 4) * 16 + lr) * 64 + kb;
      o ^= ((o >> 7) & 3) << 4;
      af[i] = *(const bf16x8*)(base + o);
    }
    if (t + 2 < NT) STG_B(t + 2, 0);
    BAR();
    WAITL();
    __builtin_amdgcn_s_setprio(1);
#pragma unroll
    for (int i = 0; i < 4; ++i)
#pragma unroll
      for (int g = 0; g < 3; ++g)
        acc[i + 4][g] = __builtin_amdgcn_mfma_f32_16x16x32_bf16(af[i], bf[g], acc[i + 4][g], 0, 0, 0);
    __builtin_amdgcn_s_setprio(0);
    BAR();
    // phase 2: kh1, i0-3 x g0-2
#pragma unroll
    for (int i = 0; i < 4; ++i) {
      int o = (wr * 128 + i * 16 + lr) * 64 + kb;
      o ^= ((o >> 7) & 3) << 4;
      af[i] = *(const bf16x8*)(base + 28672 + o);
    }
#pragma unroll
    for (int g = 0; g < 3; ++g) {
      int o = (g * 64 + wc * 16 + lr) * 64 + kb;
      o ^= ((o >> 7) & 3) << 4;
      bf[g] = *(const bf16x8*)(base + 45056 + o);
    }
    if (t + 2 < NT) STG_A(t + 2, 0);
    BAR();
    WAITL();
    __builtin_amdgcn_s_setprio(1);
#pragma unroll
    for (int i = 0; i < 4; ++i)
#pragma unroll
      for (int g = 0; g < 3; ++g)
        acc[i][g] = __builtin_amdgcn_mfma_f32_16x16x32_bf16(af[i], bf[g], acc[i][g], 0, 0, 0);
    __builtin_amdgcn_s_setprio(0);
    BAR();
    // phase 3: kh1, i4-7
#pragma unroll
    for (int i = 0; i < 4; ++i) {
      int o = (wr * 128 + (i + 4) * 16 + lr) * 64 + kb;
      o ^= ((o >> 7) & 3) << 4;
      af[i] = *(const bf16x8*)(base + 28672 + o);
    }
    if (t + 2 < NT) STG_B(t + 2, 1);
    BAR();
    WAITL();
    __builtin_amdgcn_s_setprio(1);
#pragma unroll
    for (int i = 0; i < 4; ++i)
#pragma unroll
      for (int g = 0; g < 3; ++g)
        acc[i + 4][g] = __builtin_amdgcn_mfma_f32_16x16x32_bf16(af[i], bf[g], acc[i + 4][g], 0, 0, 0);
    __builtin_amdgcn_s_setprio(0);
    if (t <= NT - 3) { WAITV(6); }
    else if (t == NT - 2) { WAITV(0); }
    BAR();
  }

  // ---- epilogue: act on fp32 z; write fp32 out (nt) + bf16 to next-A ----
  const long colg = (long)bx * 64 + wc * 16 + lr;   // 0..1023
  const float b0 = bias[colg];
  const float b1v = bias[1024 + colg];
  const float b2v = bias[2048 + colg];
#pragma unroll
  for (int i = 0; i < 8; ++i) {
#pragma unroll
    for (int qq = 0; qq < 4; ++qq) {
      long r = m0 + wr * 128 + i * 16 + lq * 4 + qq;
      float z0 = acc[i][0][qq] + b0;
      float z1 = acc[i][1][qq] + b1v;
      float z2 = acc[i][2][qq] + b2v;
      float zp = SWAP ? z1 : z0;
      float zn = SWAP ? z0 : z1;
      float p = prev[r * 1024 + colg];
      float o = (sigf(zp) * p + sigf(zn) * tanhf(z2)) * 0.5f;
      __builtin_nontemporal_store(o, &outf[r * 1024 + colg]);
      unsigned short ob = f2bf(o);
      obf1[r * obld + colg] = ob;
      if (obf2) obf2[r * obld + colg] = ob;
    }
  }
#undef STG_A
#undef STG_B
}

// ================= 8-phase 256x256 bf16 GEMM (decoder; r6/r8-verified) =================
__global__ __launch_bounds__(512, 2) void gemm8p(
    const unsigned short* __restrict__ A, int lda,
    const unsigned short* __restrict__ B, int ldb,
    const float* __restrict__ bias, float* __restrict__ C, long ldc, int K) {
  __shared__ unsigned short lds[2][4][8192];  // 128 KiB

  int bx, by;
  superblock(gridDim.x, gridDim.y, bx, by);
  const long m0 = (long)by * 256;
  const long n0 = (long)bx * 256;

  const int tid = threadIdx.x;
  const int lane = tid & 63;
  const int wave = tid >> 6;
  const int wr = wave >> 2;
  const int wc = wave & 3;
  const int lr = lane & 15;
  const int lq = lane >> 4;
  const int kb = lq * 16;

  const int o0 = tid * 16, o1 = tid * 16 + 8192;
  const int q0 = o0 ^ (((o0 >> 7) & 3) << 4);
  const int q1 = o1 ^ (((o1 >> 7) & 3) << 4);
  const char* pa0 = (const char*)(A + (m0 + (q0 >> 6)) * lda) + (q0 & 63);
  const char* pa1 = (const char*)(A + (m0 + (q1 >> 6)) * lda) + (q1 & 63);
  const char* pb0 = (const char*)(B + (n0 + (q0 >> 6)) * ldb) + (q0 & 63);
  const char* pb1 = (const char*)(B + (n0 + (q1 >> 6)) * ldb) + (q1 & 63);

  const int NT = K >> 6;

#define STG_A(t_, kh_) do { int ko = ((t_) << 7) + ((kh_) << 6);                 \
    char* d = (char*)&lds[(t_) & 1][(kh_) ? 2 : 0][0];                           \
    load16(pa0 + ko, d + o0); load16(pa1 + ko, d + o1); } while (0)
#define STG_B(t_, kh_) do { int ko = ((t_) << 7) + ((kh_) << 6);                 \
    char* d = (char*)&lds[(t_) & 1][(kh_) ? 3 : 1][0];                           \
    load16(pb0 + ko, d + o0); load16(pb1 + ko, d + o1); } while (0)

  f32x4 acc[8][4] = {};
  bf16x8 af[4], bf[4];

  STG_B(0, 0); STG_A(0, 0); STG_B(0, 1); STG_A(0, 1);
  STG_B(1, 0); STG_A(1, 0); STG_B(1, 1);
  WAITV(6);
  BAR();

  for (int t = 0; t < NT; ++t) {
    const int cur = t & 1;
    // phase 0
#pragma unroll
    for (int i = 0; i < 4; ++i) {
      int o = (wr * 128 + i * 16 + lr) * 64 + kb;
      o ^= ((o >> 7) & 3) << 4;
      af[i] = *(const bf16x8*)((const char*)&lds[cur][0][0] + o);
    }
#pragma unroll
    for (int jj = 0; jj < 4; ++jj) {
      int o = (wc * 64 + jj * 16 + lr) * 64 + kb;
      o ^= ((o >> 7) & 3) << 4;
      bf[jj] = *(const bf16x8*)((const char*)&lds[cur][1][0] + o);
    }
    if (t + 1 < NT) STG_A(t + 1, 1);
    BAR();
    WAITL();
    __builtin_amdgcn_s_setprio(1);
#pragma unroll
    for (int i = 0; i < 4; ++i)
#pragma unroll
      for (int jj = 0; jj < 4; ++jj)
        acc[i][jj] = __builtin_amdgcn_mfma_f32_16x16x32_bf16(af[i], bf[jj], acc[i][jj], 0, 0, 0);
    __builtin_amdgcn_s_setprio(0);
    BAR();
    // phase 1
#pragma unroll
    for (int i = 0; i < 4; ++i) {
      int o = (wr * 128 + (i + 4) * 16 + lr) * 64 + kb;
      o ^= ((o >> 7) & 3) << 4;
      af[i] = *(const bf16x8*)((const char*)&lds[cur][0][0] + o);
    }
    if (t + 2 < NT) STG_B(t + 2, 0);
    BAR();
    WAITL();
    __builtin_amdgcn_s_setprio(1);
#pragma unroll
    for (int i = 0; i < 4; ++i)
#pragma unroll
      for (int jj = 0; jj < 4; ++jj)
        acc[i + 4][jj] = __builtin_amdgcn_mfma_f32_16x16x32_bf16(af[i], bf[jj], acc[i + 4][jj], 0, 0, 0);
    __builtin_amdgcn_s_setprio(0);
    BAR();
    // phase 2
#pragma unroll
    for (int i = 0; i < 4; ++i) {
      int o = (wr * 128 + i * 16 + lr) * 64 + kb;
      o ^= ((o >> 7) & 3) << 4;
      af[i] = *(const bf16x8*)((const char*)&lds[cur][2][0] + o);
    }
#pragma unroll
    for (int jj = 0; jj < 4; ++jj) {
      int o = (wc * 64 + jj * 16 + lr) * 64 + kb;
      o ^= ((o >> 7) & 3) << 4;
      bf[jj] = *(const bf16x8*)((const char*)&lds[cur][3][0] + o);
    }
    if (t + 2 < NT) STG_A(t + 2, 0);
    BAR();
    WAITL();
    __builtin_amdgcn_s_setprio(1);
#pragma unroll
    for (int i = 0; i < 4; ++i)
#pragma unroll
      for (int jj = 0; jj < 4; ++jj)
        acc[i][jj] = __builtin_amdgcn_mfma_f32_16x16x32_bf16(af[i], bf[jj], acc[i][jj], 0, 0, 0);
    __builtin_amdgcn_s_setprio(0);
    BAR();
    // phase 3
#pragma unroll
    for (int i = 0; i < 4; ++i) {
      int o = (wr * 128 + (i + 4) * 16 + lr) * 64 + kb;
      o ^= ((o >> 7) & 3) << 4;
      af[i] = *(const bf16x8*)((const char*)&lds[cur][2][0] + o);
    }
    if (t + 2 < NT) STG_B(t + 2, 1);
    BAR();
    WAITL();
    __builtin_amdgcn_s_setprio(1);
#pragma unroll
    for (int i = 0; i < 4; ++i)
#pragma unroll
      for (int jj = 0; jj < 4; ++jj)
        acc[i + 4][jj] = __builtin_amdgcn_mfma_f32_16x16x32_bf16(af[i], bf[jj], acc[i + 4][jj], 0, 0, 0);
    __builtin_amdgcn_s_setprio(0);
    if (t <= NT - 3) { WAITV(6); }
    else if (t == NT - 2) { WAITV(0); }
    BAR();
  }

  float* Tw = (float*)&lds[0][0][0] + wave * 2176;   // two [16][68] f32 tiles
  f32x4 bv4 = *(const f32x4*)&bias[n0 + wc * 64 + lr * 4];
#pragma unroll
  for (int i = 0; i < 8; ++i) {
    float* T = Tw + (i & 1) * 1088;
#pragma unroll
    for (int jj = 0; jj < 4; ++jj)
#pragma unroll
      for (int qq = 0; qq < 4; ++qq)
        T[(lq * 4 + qq) * 68 + jj * 16 + lr] = acc[i][jj][qq];
#pragma unroll
    for (int s = 0; s < 4; ++s) {
      f32x4 v = *(const f32x4*)&T[(s * 4 + lq) * 68 + lr * 4];
      v += bv4;
      long row = m0 + wr * 128 + i * 16 + s * 4 + lq;
      __builtin_nontemporal_store(v, (f32x4*)&C[row * ldc + n0 + wc * 64 + lr * 4]);
    }
  }
#undef STG_A
#undef STG_B
}

extern "C" void kernel_launch(void* const* d_in, const int* in_sizes, int n_in,
                              void* d_out, int out_size, void* d_ws, size_t ws_size,
                              hipStream_t stream) {
  const int*   ids  = (const int*)d_in[0];
  const float* c1   = (const float*)d_in[1];
  const float* h1   = (const float*)d_in[2];
  const float* c2   = (const float*)d_in[3];
  const float* h2   = (const float*)d_in[4];
  const float* embW = (const float*)d_in[5];
  const float* W1   = (const float*)d_in[6];
  const float* b1   = (const float*)d_in[7];
  const float* W2   = (const float*)d_in[8];
  const float* b2   = (const float*)d_in[9];
  const float* decW = (const float*)d_in[10];
  const float* decb = (const float*)d_in[11];
  float* out = (float*)d_out;

  char* ws = (char*)d_ws;
  unsigned short* A0   = (unsigned short*)(ws);
  unsigned short* A1   = (unsigned short*)(ws + 16777216L);
  unsigned short* A2   = (unsigned short*)(ws + 33554432L);
  unsigned short* cWb1 = (unsigned short*)(ws + 50331648L);
  unsigned short* cWb2 = (unsigned short*)(ws + 75497472L);
  unsigned short* dWb  = (unsigned short*)(ws + 50331648L);  // after cWb* die
  unsigned short* A4   = A1;                                  // packed [4096][1024]

  float* out_dec = out;
  float* out_c1  = out + 131072000L;
  float* out_h1  = out_c1 + 4194304L;
  float* out_c2  = out_h1 + 4194304L;
  float* out_h2  = out_c2 + 4194304L;

  dim3 blk(256), gblk(512);
  dim3 gcell(16, 16);                          // 256 blocks = 100% CU

  // ---- pre: convW1 + convW2 + seed A0/A1/A2 ----
  fused_pre<<<dim3(28672), blk, 0, stream>>>(W1, cWb1, W2, cWb2, ids, embW, h1, h2,
                                             A0, A1, A2);

  // ---- cells (act fused in epilogue) ----
  gemm8f<0><<<gcell, gblk, 0, stream>>>(A0, cWb1, b1, c1,
                                        out_c1, A1 + 1024, nullptr, 2048);
  gemm8f<1><<<gcell, gblk, 0, stream>>>(A1, cWb1 + 3072L * 2048, b1 + 3072, h1,
                                        out_h1, A2, A0, 2048);
  gemm8f<0><<<gcell, gblk, 0, stream>>>(A2, cWb2, b2, c2,
                                        out_c2, A0 + 1024, nullptr, 2048);
  gemm8f<1><<<gcell, gblk, 0, stream>>>(A0, cWb2 + 3072L * 2048, b2 + 3072, h2,
                                        out_h2, A4, nullptr, 1024);

  // ---- decoder: convert weights, then 256x256 GEMM ----
  convbf<<<dim3(32000), blk, 0, stream>>>(decW, dWb, 32000L * 1024 / 4);
  {
    dim3 g(125, 16);                           // 2000 blocks (%8==0)
    gemm8p<<<g, gblk, 0, stream>>>(A4, 1024, dWb, 1024, decb, out_dec, 32000, 1024);
  }
}

// Round 10
// 598.504 us; speedup vs baseline: 1.1131x; 1.0167x over previous
//
#include <hip/hip_runtime.h>

// RevRNN forward on MI355X — round 10: read-ahead pipelined K-loop.
// Each phase: {read NEXT phase's frags (ping-pong regs) | stage 2 loads |
// sched_barrier | MFMA this phase's frags | counted WAITV | 1 barrier}.
// 4 barriers/tile (was 8); ds_read latency hidden under MFMA.
// Ledger (stages at r9-verified spots, 2 loads/phase):
//   P0: STG_A(t+1,kh1)  P1: STG_B(t+2,kh0)  P2: STG_A(t+2,kh0)  P3: STG_B(t+2,kh1)
//   WAITV(8) end-P0 (covers P1 reads: A_k1(t)@P0(t-1)=8-deep, B_k1(t)@P3(t-2)=10-deep)
//   WAITV(8) end-P2 (covers P3 reads: A_k0(t+1)@P2(t-1)=8, B_k0(t+1)@P1(t-1)=10)
//   tail: end-P2(NT-2)->WAITV(4); end-P0(NT-1)->WAITV(0). Prologue 14 loads->WAITV(10).
// All sub-buffer overwrites remain >=1 barrier after their last reader (checked).
//
// ws layout unchanged from r9 (peak 115.9 MB):
//   A0@0  A1@16M  A2@33M  cWb1@50M  cWb2@75M  dWb@50M(after cWb die)  A4=A1 packed

typedef __attribute__((ext_vector_type(4))) float f32x4;
typedef __attribute__((ext_vector_type(8))) short bf16x8;
typedef __attribute__((ext_vector_type(4))) unsigned short u16x4;

__device__ __forceinline__ unsigned short f2bf(float x) {
  unsigned u = __float_as_uint(x);
  return (unsigned short)((u + 0x7fffu + ((u >> 16) & 1u)) >> 16);  // RNE
}
__device__ __forceinline__ u16x4 cvt4v(f32x4 v) {
  u16x4 h;
  h[0] = f2bf(v[0]); h[1] = f2bf(v[1]); h[2] = f2bf(v[2]); h[3] = f2bf(v[3]);
  return h;
}
__device__ __forceinline__ float sigf(float x) { return 1.0f / (1.0f + expf(-x)); }

__device__ __forceinline__ void conv_chunk(const float* __restrict__ src,
                                           unsigned short* __restrict__ dst,
                                           long i, long n4) {
  if (i >= n4) return;
  f32x4 v = __builtin_nontemporal_load(reinterpret_cast<const f32x4*>(src) + i);
  reinterpret_cast<u16x4*>(dst)[i] = cvt4v(v);
}

__global__ void convbf(const float* __restrict__ src, unsigned short* __restrict__ dst, long n4) {
  long i = (long)blockIdx.x * blockDim.x + threadIdx.x;
  if (i >= n4) return;
  conv_chunk(src, dst, i, n4);
}

// ---- fused: convW1 + convW2 + gather/seed A-buffers ----
__global__ void fused_pre(const float* __restrict__ W1, unsigned short* __restrict__ cWb1,
                          const float* __restrict__ W2, unsigned short* __restrict__ cWb2,
                          const int* __restrict__ ids, const float* __restrict__ embW,
                          const float* __restrict__ h1, const float* __restrict__ h2,
                          unsigned short* __restrict__ A0, unsigned short* __restrict__ A1,
                          unsigned short* __restrict__ A2) {
  const long n4 = 6L * 1024 * 2048 / 4;
  int b = blockIdx.x;
  int t = threadIdx.x;
  if (b < 12288) {
    conv_chunk(W1, cWb1, (long)b * 256 + t, n4);
  } else if (b < 24576) {
    conv_chunk(W2, cWb2, (long)(b - 12288) * 256 + t, n4);
  } else {
    int r = b - 24576;
    long erow = (long)ids[r] * 1024;
    u16x4 e = cvt4v(reinterpret_cast<const f32x4*>(embW + erow)[t]);
    reinterpret_cast<u16x4*>(A0 + (long)r * 2048)[t] = e;
    reinterpret_cast<u16x4*>(A1 + (long)r * 2048)[t] = e;
    reinterpret_cast<u16x4*>(A0 + (long)r * 2048 + 1024)[t] =
        cvt4v(reinterpret_cast<const f32x4*>(h1 + (long)r * 1024)[t]);
    reinterpret_cast<u16x4*>(A2 + (long)r * 2048 + 1024)[t] =
        cvt4v(reinterpret_cast<const f32x4*>(h2 + (long)r * 1024)[t]);
  }
}

// ---- async global->LDS 16B ----
__device__ __forceinline__ void load16(const void* g, void* l) {
  __builtin_amdgcn_global_load_lds((const __attribute__((address_space(1))) unsigned int*)g,
                                   (__attribute__((address_space(3))) unsigned int*)l,
                                   16, 0, 0);
}

#define WAITV(n) do { asm volatile("s_waitcnt vmcnt(" #n ")" ::: "memory");      \
    __builtin_amdgcn_sched_barrier(0); } while (0)
#define BAR() __builtin_amdgcn_s_barrier()
#define SCHED0() __builtin_amdgcn_sched_barrier(0)

// ---- bijective 2D XCD super-block mapping (nwg % 8 == 0) ----
__device__ __forceinline__ void superblock(int gx, int gy, int& bx, int& by) {
  const int nwg = gx * gy;
  int bid = blockIdx.y * gx + blockIdx.x;
  const int q = nwg >> 3;
  const int x = bid & 7, j = bid >> 3;
  const int p = x >> 1, half = x & 1;
  const int w0 = (gx + 1) >> 1;
  int byl;
  if ((w0 << 2) == q) {
    bx = half * w0 + (j >> 2);
    byl = j & 3;
  } else {
    if (j < q - 2) { bx = (half ? w0 : 0) + (j >> 2); byl = j & 3; }
    else { bx = w0 - 1; byl = (half ? 2 : 0) + (j - (q - 2)); }
  }
  by = p * 4 + byl;
}

// ========== fused cell GEMM+act (read-ahead pipelined) ==========
// Block 256 rows x 64 z-cols x 3 gates; LDS subs: A0@0 B0@16384 A1@28672 B1@45056
// per 56KB buffer (x2). B panel staged with dup-write trick (2 loads/stage).
template <int SWAP>
__global__ __launch_bounds__(512, 2) void gemm8f(
    const unsigned short* __restrict__ A,
    const unsigned short* __restrict__ B,
    const float* __restrict__ bias,
    const float* __restrict__ prev,
    float* __restrict__ outf,
    unsigned short* __restrict__ obf1,
    unsigned short* __restrict__ obf2, long obld) {
  __shared__ unsigned short lds[57344];  // 112 KiB

  int bx, by;
  superblock(gridDim.x, gridDim.y, bx, by);   // gx=16 -> even path
  const long m0 = (long)by * 256;

  const int tid = threadIdx.x;
  const int lane = tid & 63;
  const int wave = tid >> 6;
  const int wr = wave >> 2;                    // 0..1 (128 rows)
  const int wc = wave & 3;                     // 0..3 (16 z-cols each)
  const int lr = lane & 15;
  const int lq = lane >> 4;
  const int kb = lq * 16;

  const int o0 = tid * 16, o1 = tid * 16 + 8192;
  const int q0 = o0 ^ (((o0 >> 7) & 3) << 4);
  const int q1 = o1 ^ (((o1 >> 7) & 3) << 4);
  const char* pa0 = (const char*)(A + (m0 + (q0 >> 6)) * 2048) + (q0 & 63);
  const char* pa1 = (const char*)(A + (m0 + (q1 >> 6)) * 2048) + (q1 & 63);
  const int oB1 = 8192 + (tid & 255) * 16;     // waves 4-7 mirror waves 0-3
  const int qB1 = oB1 ^ (((oB1 >> 7) & 3) << 4);
  const int lrow0 = q0 >> 6, lrow1 = qB1 >> 6;
  const long grow0 = (long)(lrow0 >> 6) * 1024 + bx * 64 + (lrow0 & 63);
  const long grow1 = (long)(lrow1 >> 6) * 1024 + bx * 64 + (lrow1 & 63);
  const char* pb0 = (const char*)(B + grow0 * 2048) + (q0 & 63);
  const char* pb1 = (const char*)(B + grow1 * 2048) + (qB1 & 63);

  const int NT = 32;                           // K=2048, BK=64

#define STG_A(t_, kh_) do { int ko = ((t_) << 7) + ((kh_) << 6);                 \
    char* base_ = (char*)&lds[0] + ((t_) & 1) * 57344;                           \
    char* dst = base_ + ((kh_) ? 28672 : 0);                                     \
    load16(pa0 + ko, dst + o0); load16(pa1 + ko, dst + o1); } while (0)
#define STG_B(t_, kh_) do { int ko = ((t_) << 7) + ((kh_) << 6);                 \
    char* base_ = (char*)&lds[0] + ((t_) & 1) * 57344;                           \
    char* dst = base_ + ((kh_) ? 45056 : 16384);                                 \
    load16(pb0 + ko, dst + o0); load16(pb1 + ko, dst + oB1); } while (0)
#define RDA(dst, bp, soff, ih) do {                                              \
    _Pragma("unroll") for (int i_ = 0; i_ < 4; ++i_) {                           \
      int o_ = (wr * 128 + ((ih) * 4 + i_) * 16 + lr) * 64 + kb;                 \
      o_ ^= ((o_ >> 7) & 3) << 4;                                                \
      dst[i_] = *(const bf16x8*)((bp) + (soff) + o_); } } while (0)
#define RDB(dst, bp, soff) do {                                                  \
    _Pragma("unroll") for (int g_ = 0; g_ < 3; ++g_) {                           \
      int o_ = (g_ * 64 + wc * 16 + lr) * 64 + kb;                               \
      o_ ^= ((o_ >> 7) & 3) << 4;                                                \
      dst[g_] = *(const bf16x8*)((bp) + (soff) + o_); } } while (0)
#define MF12(ar, af_, bf_) do {                                                  \
    _Pragma("unroll") for (int i_ = 0; i_ < 4; ++i_)                             \
    _Pragma("unroll") for (int g_ = 0; g_ < 3; ++g_)                             \
      acc[(ar) + i_][g_] = __builtin_amdgcn_mfma_f32_16x16x32_bf16(              \
          af_[i_], bf_[g_], acc[(ar) + i_][g_], 0, 0, 0); } while (0)

  f32x4 acc[8][3] = {};
  bf16x8 af1[4], af2[4], bfA[3], bfB[3];

  STG_B(0, 0); STG_A(0, 0); STG_B(0, 1); STG_A(0, 1);
  STG_B(1, 0); STG_A(1, 0); STG_B(1, 1);
  WAITV(10);
  BAR();
  {
    const char* b0 = (const char*)&lds[0];
    RDA(af1, b0, 0, 0);          // A kh0 i0-3 (tile 0)
    RDB(bfA, b0, 16384);         // B kh0 (tile 0)
  }

  for (int t = 0; t < NT; ++t) {
    const char* base = (const char*)&lds[0] + (t & 1) * 57344;
    const char* baseN = (const char*)&lds[0] + ((t + 1) & 1) * 57344;
    // ---- P0: MFMA kh0 i0-3; read kh0 i4-7 ----
    RDA(af2, base, 0, 1);
    if (t + 1 < NT) STG_A(t + 1, 1);
    SCHED0();
    __builtin_amdgcn_s_setprio(1);
    MF12(0, af1, bfA);
    __builtin_amdgcn_s_setprio(0);
    if (t < NT - 1) { WAITV(8); } else { WAITV(0); }
    BAR();
    // ---- P1: MFMA kh0 i4-7; read kh1 i0-3 + B kh1 ----
    RDA(af1, base, 28672, 0);
    RDB(bfB, base, 45056);
    if (t + 2 < NT) STG_B(t + 2, 0);
    SCHED0();
    __builtin_amdgcn_s_setprio(1);
    MF12(4, af2, bfA);
    __builtin_amdgcn_s_setprio(0);
    BAR();
    // ---- P2: MFMA kh1 i0-3; read kh1 i4-7 ----
    RDA(af2, base, 28672, 1);
    if (t + 2 < NT) STG_A(t + 2, 0);
    SCHED0();
    __builtin_amdgcn_s_setprio(1);
    MF12(0, af1, bfB);
    __builtin_amdgcn_s_setprio(0);
    if (t < NT - 2) { WAITV(8); } else if (t == NT - 2) { WAITV(4); }
    BAR();
    // ---- P3: MFMA kh1 i4-7; read next-tile kh0 ----
    if (t + 1 < NT) {
      RDA(af1, baseN, 0, 0);
      RDB(bfA, baseN, 16384);
    }
    if (t + 2 < NT) STG_B(t + 2, 1);
    SCHED0();
    __builtin_amdgcn_s_setprio(1);
    MF12(4, af2, bfB);
    __builtin_amdgcn_s_setprio(0);
    BAR();
  }

  // ---- epilogue: act on fp32 z; write fp32 out (nt) + bf16 to next-A ----
  const long colg = (long)bx * 64 + wc * 16 + lr;
  const float b0v = bias[colg];
  const float b1v = bias[1024 + colg];
  const float b2v = bias[2048 + colg];
#pragma unroll
  for (int i = 0; i < 8; ++i) {
#pragma unroll
    for (int qq = 0; qq < 4; ++qq) {
      long r = m0 + wr * 128 + i * 16 + lq * 4 + qq;
      float z0 = acc[i][0][qq] + b0v;
      float z1 = acc[i][1][qq] + b1v;
      float z2 = acc[i][2][qq] + b2v;
      float zp = SWAP ? z1 : z0;
      float zn = SWAP ? z0 : z1;
      float p = prev[r * 1024 + colg];
      float o = (sigf(zp) * p + sigf(zn) * tanhf(z2)) * 0.5f;
      __builtin_nontemporal_store(o, &outf[r * 1024 + colg]);
      unsigned short ob = f2bf(o);
      obf1[r * obld + colg] = ob;
      if (obf2) obf2[r * obld + colg] = ob;
    }
  }
#undef STG_A
#undef STG_B
#undef RDA
#undef RDB
#undef MF12
}

// ========== decoder GEMM 256x256 (read-ahead pipelined) ==========
__global__ __launch_bounds__(512, 2) void gemm8p(
    const unsigned short* __restrict__ A, int lda,
    const unsigned short* __restrict__ B, int ldb,
    const float* __restrict__ bias, float* __restrict__ C, long ldc, int K) {
  __shared__ unsigned short lds[2][4][8192];  // 128 KiB

  int bx, by;
  superblock(gridDim.x, gridDim.y, bx, by);
  const long m0 = (long)by * 256;
  const long n0 = (long)bx * 256;

  const int tid = threadIdx.x;
  const int lane = tid & 63;
  const int wave = tid >> 6;
  const int wr = wave >> 2;
  const int wc = wave & 3;
  const int lr = lane & 15;
  const int lq = lane >> 4;
  const int kb = lq * 16;

  const int o0 = tid * 16, o1 = tid * 16 + 8192;
  const int q0 = o0 ^ (((o0 >> 7) & 3) << 4);
  const int q1 = o1 ^ (((o1 >> 7) & 3) << 4);
  const char* pa0 = (const char*)(A + (m0 + (q0 >> 6)) * lda) + (q0 & 63);
  const char* pa1 = (const char*)(A + (m0 + (q1 >> 6)) * lda) + (q1 & 63);
  const char* pb0 = (const char*)(B + (n0 + (q0 >> 6)) * ldb) + (q0 & 63);
  const char* pb1 = (const char*)(B + (n0 + (q1 >> 6)) * ldb) + (q1 & 63);

  const int NT = K >> 6;

#define STG_A(t_, kh_) do { int ko = ((t_) << 7) + ((kh_) << 6);                 \
    char* d = (char*)&lds[(t_) & 1][(kh_) ? 2 : 0][0];                           \
    load16(pa0 + ko, d + o0); load16(pa1 + ko, d + o1); } while (0)
#define STG_B(t_, kh_) do { int ko = ((t_) << 7) + ((kh_) << 6);                 \
    char* d = (char*)&lds[(t_) & 1][(kh_) ? 3 : 1][0];                           \
    load16(pb0 + ko, d + o0); load16(pb1 + ko, d + o1); } while (0)
#define RDA(dst, bp, soff, ih) do {                                              \
    _Pragma("unroll") for (int i_ = 0; i_ < 4; ++i_) {                           \
      int o_ = (wr * 128 + ((ih) * 4 + i_) * 16 + lr) * 64 + kb;                 \
      o_ ^= ((o_ >> 7) & 3) << 4;                                                \
      dst[i_] = *(const bf16x8*)((bp) + (soff) + o_); } } while (0)
#define RDB(dst, bp, soff) do {                                                  \
    _Pragma("unroll") for (int j_ = 0; j_ < 4; ++j_) {                           \
      int o_ = (wc * 64 + j_ * 16 + lr) * 64 + kb;                               \
      o_ ^= ((o_ >> 7) & 3) << 4;                                                \
      dst[j_] = *(const bf16x8*)((bp) + (soff) + o_); } } while (0)
#define MF16(ar, af_, bf_) do {                                                  \
    _Pragma("unroll") for (int i_ = 0; i_ < 4; ++i_)                             \
    _Pragma("unroll") for (int j_ = 0; j_ < 4; ++j_)                             \
      acc[(ar) + i_][j_] = __builtin_amdgcn_mfma_f32_16x16x32_bf16(              \
          af_[i_], bf_[j_], acc[(ar) + i_][j_], 0, 0, 0); } while (0)

  f32x4 acc[8][4] = {};
  bf16x8 af1[4], af2[4], bfA[4], bfB[4];

  STG_B(0, 0); STG_A(0, 0); STG_B(0, 1); STG_A(0, 1);
  STG_B(1, 0); STG_A(1, 0); STG_B(1, 1);
  WAITV(10);
  BAR();
  {
    const char* b0 = (const char*)&lds[0][0][0];
    RDA(af1, b0, 0, 0);
    RDB(bfA, b0, 16384);
  }

  for (int t = 0; t < NT; ++t) {
    const char* base = (const char*)&lds[0][0][0] + (t & 1) * 65536;
    const char* baseN = (const char*)&lds[0][0][0] + ((t + 1) & 1) * 65536;
    // ---- P0 ----
    RDA(af2, base, 0, 1);
    if (t + 1 < NT) STG_A(t + 1, 1);
    SCHED0();
    __builtin_amdgcn_s_setprio(1);
    MF16(0, af1, bfA);
    __builtin_amdgcn_s_setprio(0);
    if (t < NT - 1) { WAITV(8); } else { WAITV(0); }
    BAR();
    // ---- P1 ----
    RDA(af1, base, 32768, 0);
    RDB(bfB, base, 49152);
    if (t + 2 < NT) STG_B(t + 2, 0);
    SCHED0();
    __builtin_amdgcn_s_setprio(1);
    MF16(4, af2, bfA);
    __builtin_amdgcn_s_setprio(0);
    BAR();
    // ---- P2 ----
    RDA(af2, base, 32768, 1);
    if (t + 2 < NT) STG_A(t + 2, 0);
    SCHED0();
    __builtin_amdgcn_s_setprio(1);
    MF16(0, af1, bfB);
    __builtin_amdgcn_s_setprio(0);
    if (t < NT - 2) { WAITV(8); } else if (t == NT - 2) { WAITV(4); }
    BAR();
    // ---- P3 ----
    if (t + 1 < NT) {
      RDA(af1, baseN, 0, 0);
      RDB(bfA, baseN, 16384);
    }
    if (t + 2 < NT) STG_B(t + 2, 1);
    SCHED0();
    __builtin_amdgcn_s_setprio(1);
    MF16(4, af2, bfB);
    __builtin_amdgcn_s_setprio(0);
    BAR();
  }

  // ---- epilogue: per-wave LDS transpose -> coalesced nt stores ----
  float* Tw = (float*)&lds[0][0][0] + wave * 2176;   // two [16][68] f32 tiles
  f32x4 bv4 = *(const f32x4*)&bias[n0 + wc * 64 + lr * 4];
#pragma unroll
  for (int i = 0; i < 8; ++i) {
    float* T = Tw + (i & 1) * 1088;
#pragma unroll
    for (int jj = 0; jj < 4; ++jj)
#pragma unroll
      for (int qq = 0; qq < 4; ++qq)
        T[(lq * 4 + qq) * 68 + jj * 16 + lr] = acc[i][jj][qq];
#pragma unroll
    for (int s = 0; s < 4; ++s) {
      f32x4 v = *(const f32x4*)&T[(s * 4 + lq) * 68 + lr * 4];
      v += bv4;
      long row = m0 + wr * 128 + i * 16 + s * 4 + lq;
      __builtin_nontemporal_store(v, (f32x4*)&C[row * ldc + n0 + wc * 64 + lr * 4]);
    }
  }
#undef STG_A
#undef STG_B
#undef RDA
#undef RDB
#undef MF16
}

extern "C" void kernel_launch(void* const* d_in, const int* in_sizes, int n_in,
                              void* d_out, int out_size, void* d_ws, size_t ws_size,
                              hipStream_t stream) {
  const int*   ids  = (const int*)d_in[0];
  const float* c1   = (const float*)d_in[1];
  const float* h1   = (const float*)d_in[2];
  const float* c2   = (const float*)d_in[3];
  const float* h2   = (const float*)d_in[4];
  const float* embW = (const float*)d_in[5];
  const float* W1   = (const float*)d_in[6];
  const float* b1   = (const float*)d_in[7];
  const float* W2   = (const float*)d_in[8];
  const float* b2   = (const float*)d_in[9];
  const float* decW = (const float*)d_in[10];
  const float* decb = (const float*)d_in[11];
  float* out = (float*)d_out;

  char* ws = (char*)d_ws;
  unsigned short* A0   = (unsigned short*)(ws);
  unsigned short* A1   = (unsigned short*)(ws + 16777216L);
  unsigned short* A2   = (unsigned short*)(ws + 33554432L);
  unsigned short* cWb1 = (unsigned short*)(ws + 50331648L);
  unsigned short* cWb2 = (unsigned short*)(ws + 75497472L);
  unsigned short* dWb  = (unsigned short*)(ws + 50331648L);  // after cWb* die
  unsigned short* A4   = A1;                                  // packed [4096][1024]

  float* out_dec = out;
  float* out_c1  = out + 131072000L;
  float* out_h1  = out_c1 + 4194304L;
  float* out_c2  = out_h1 + 4194304L;
  float* out_h2  = out_c2 + 4194304L;

  dim3 blk(256), gblk(512);
  dim3 gcell(16, 16);                          // 256 blocks = 100% CU

  // ---- pre: convW1 + convW2 + seed A0/A1/A2 ----
  fused_pre<<<dim3(28672), blk, 0, stream>>>(W1, cWb1, W2, cWb2, ids, embW, h1, h2,
                                             A0, A1, A2);

  // ---- cells (act fused in epilogue) ----
  gemm8f<0><<<gcell, gblk, 0, stream>>>(A0, cWb1, b1, c1,
                                        out_c1, A1 + 1024, nullptr, 2048);
  gemm8f<1><<<gcell, gblk, 0, stream>>>(A1, cWb1 + 3072L * 2048, b1 + 3072, h1,
                                        out_h1, A2, A0, 2048);
  gemm8f<0><<<gcell, gblk, 0, stream>>>(A2, cWb2, b2, c2,
                                        out_c2, A0 + 1024, nullptr, 2048);
  gemm8f<1><<<gcell, gblk, 0, stream>>>(A0, cWb2 + 3072L * 2048, b2 + 3072, h2,
                                        out_h2, A4, nullptr, 1024);

  // ---- decoder: convert weights, then 256x256 GEMM ----
  convbf<<<dim3(32000), blk, 0, stream>>>(decW, dWb, 32000L * 1024 / 4);
  {
    dim3 g(125, 16);                           // 2000 blocks (%8==0)
    gemm8p<<<g, gblk, 0, stream>>>(A4, 1024, dWb, 1024, decb, out_dec, 32000, 1024);
  }
}